// Round 8
// baseline (482.177 us; speedup 1.0000x reference)
//
#include <hip/hip_runtime.h>

#define HH 512
#define WW 512
#define SS (HH * WW)          // elements per plane (2^18)
#define P16N (16 * SS)        // 16 planes (2^22)
#define PADW 576              // skewed LDS row: addr(j) = j + (j>>3)

constexpr float FINF = 3.402823466e38f;

__device__ __forceinline__ int swz(int j) { return j + (j >> 3); }

__device__ __forceinline__ float gray1(float r, float g, float b) {
    return 0.299f * r + 0.587f * g + 0.114f * b;
}

// inverse of small integer c in [R+1, 2R+1] without v_div (cmp+cndmask chain)
template <int R>
__device__ __forceinline__ float invsmall(int c) {
    float r = 1.f / (float)(2 * R + 1);
    #pragma unroll
    for (int v = R + 1; v < 2 * R + 1; ++v)
        if (c == v) r = 1.f / (float)v;      // compile-time constants
    return r;
}

// ---------------- grad (gray fused, both dirs, 4 px/thread) ----------------
__global__ __launch_bounds__(256) void grad_both(const float* __restrict__ rgb,
                                                 float* __restrict__ dst,
                                                 int gxp0, int gyp0, int dirsel) {
    int sp = blockIdx.x * 256 + threadIdx.x;
    int idx = sp << 2;                             // [0, P16N)
    int img = idx >> 18;
    int pix = idx & (SS - 1);
    int i = pix >> 9, j0 = pix & (WW - 1);
    const float* p0 = rgb + (size_t)img * 3 * SS + pix;

    float4 r = *(const float4*)p0;
    float4 g = *(const float4*)(p0 + SS);
    float4 b = *(const float4*)(p0 + 2 * SS);
    float4 gy4 = make_float4(gray1(r.x, g.x, b.x), gray1(r.y, g.y, b.y),
                             gray1(r.z, g.z, b.z), gray1(r.w, g.w, b.w));
    if (dirsel != 1) {
        float grs = 0.f;
        if (j0 + 4 < WW) grs = gray1(p0[4], p0[SS + 4], p0[2 * SS + 4]);
        float4 gx = make_float4(gy4.x - gy4.y, gy4.y - gy4.z, gy4.z - gy4.w, gy4.w - grs);
        *(float4*)(dst + (size_t)(gxp0 + img) * SS + pix) = gx;
    }
    if (dirsel != 0) {
        float4 gd = make_float4(0.f, 0.f, 0.f, 0.f);
        if (i < HH - 1) {
            float4 r2 = *(const float4*)(p0 + WW);
            float4 g2 = *(const float4*)(p0 + SS + WW);
            float4 b2 = *(const float4*)(p0 + 2 * SS + WW);
            gd = make_float4(gray1(r2.x, g2.x, b2.x), gray1(r2.y, g2.y, b2.y),
                             gray1(r2.z, g2.z, b2.z), gray1(r2.w, g2.w, b2.w));
        }
        float4 gy = make_float4(gy4.x - gd.x, gy4.y - gd.y, gy4.z - gd.z, gy4.w - gd.w);
        *(float4*)(dst + (size_t)(gyp0 + img) * SS + pix) = gy;
    }
}

// ---------------- dual max+min pool (column-first, skewed LDS) ----------------
// SINGLE ring buffer rb[W]; exact wrap-counted validity mask (compile-time
// except i0). Phase-split over ONE LDS buffer (36864 B -> 4 blocks/CU):
// vertical max -> LDS, min -> regs; hmax -> dmax; reload; hmin -> dmin.
template <bool PREABS, int R, int TH>
__global__ __launch_bounds__(256, 4) void dual_pool(const float* __restrict__ src,
                                                    float* __restrict__ dmax,
                                                    float* __restrict__ dmin) {
    constexpr int TILES = HH / TH;
    constexpr int W = 2 * R + 1;
    constexpr int NS = (TH * 64) / 256;
    __shared__ float lbuf[TH * PADW];

    const int plane = blockIdx.x / TILES;
    const int tile  = blockIdx.x % TILES;
    const int i0    = tile * TH;
    const size_t pbase = (size_t)plane * SS;
    const float* sp = src + pbase;
    const int t = threadIdx.x;
    const int ca = swz(2 * t);                     // ca+1 == swz(2t+1)

    float2 rb[W];
    float2 keepmn[TH];
    auto ld = [&](int gi) -> float2 {
        float2 u = ((const float2*)(sp + (size_t)gi * WW))[t];
        if (PREABS) { u.x = fabsf(u.x); u.y = fabsf(u.y); }
        return u;
    };
    #pragma unroll
    for (int k = 0; k < W; ++k)
        if ((unsigned)(i0 - R + k) < (unsigned)HH) rb[k] = ld(i0 - R + k);
    #pragma unroll
    for (int oi = 0; oi < TH; ++oi) {
        if (oi > 0) {
            if ((unsigned)(i0 + oi + R) < (unsigned)HH) rb[(oi - 1) % W] = ld(i0 + oi + R);
        }
        float2 mx = make_float2(-FINF, -FINF), mn = make_float2(FINF, FINF);
        #pragma unroll
        for (int k = 0; k < W; ++k) {
            int wrap = (oi > k) ? ((oi - 1 - k) / W + 1) : 0;   // compile-time
            int ro = k - R + wrap * W;                          // exact row in slot k
            if ((unsigned)(i0 + ro) < (unsigned)HH) {           // block-uniform branch
                mx.x = fmaxf(mx.x, rb[k].x); mx.y = fmaxf(mx.y, rb[k].y);
                mn.x = fminf(mn.x, rb[k].x); mn.y = fminf(mn.y, rb[k].y);
            }
        }
        lbuf[oi * PADW + ca] = mx.x; lbuf[oi * PADW + ca + 1] = mx.y;
        keepmn[oi] = mn;
    }
    __syncthreads();

    // horizontal max -> dmax
    #pragma unroll
    for (int si = 0; si < NS; ++si) {
        int s = si * 256 + t;
        int rr = s >> 6, j0 = (s & 63) << 3;
        const float* rx = &lbuf[rr * PADW];
        float vx[2 * R + 8];
        #pragma unroll
        for (int k = 0; k < 2 * R + 8; ++k) {
            int jj = j0 - R + k;
            bool ok = (unsigned)jj < (unsigned)WW;
            int jc = swz(min(max(jj, 0), WW - 1));
            vx[k] = ok ? rx[jc] : -FINF;
        }
        float ox[8];
        #pragma unroll
        for (int d = 0; d < 8; ++d) {
            float mx = vx[d];
            #pragma unroll
            for (int k = 1; k <= 2 * R; ++k) mx = fmaxf(mx, vx[d + k]);
            ox[d] = mx;
        }
        size_t o = pbase + (size_t)(i0 + rr) * WW + j0;
        ((float4*)&dmax[o])[0] = make_float4(ox[0], ox[1], ox[2], ox[3]);
        ((float4*)&dmax[o])[1] = make_float4(ox[4], ox[5], ox[6], ox[7]);
    }
    __syncthreads();

    // swap in the vertical-min column results
    #pragma unroll
    for (int oi = 0; oi < TH; ++oi) {
        lbuf[oi * PADW + ca] = keepmn[oi].x;
        lbuf[oi * PADW + ca + 1] = keepmn[oi].y;
    }
    __syncthreads();

    // horizontal min -> dmin
    #pragma unroll
    for (int si = 0; si < NS; ++si) {
        int s = si * 256 + t;
        int rr = s >> 6, j0 = (s & 63) << 3;
        const float* rn = &lbuf[rr * PADW];
        float vn[2 * R + 8];
        #pragma unroll
        for (int k = 0; k < 2 * R + 8; ++k) {
            int jj = j0 - R + k;
            bool ok = (unsigned)jj < (unsigned)WW;
            int jc = swz(min(max(jj, 0), WW - 1));
            vn[k] = ok ? rn[jc] : FINF;
        }
        float on[8];
        #pragma unroll
        for (int d = 0; d < 8; ++d) {
            float mn = vn[d];
            #pragma unroll
            for (int k = 1; k <= 2 * R; ++k) mn = fminf(mn, vn[d + k]);
            on[d] = mn;
        }
        size_t o = pbase + (size_t)(i0 + rr) * WW + j0;
        ((float4*)&dmin[o])[0] = make_float4(on[0], on[1], on[2], on[3]);
        ((float4*)&dmin[o])[1] = make_float4(on[4], on[5], on[6], on[7]);
    }
}

// ---------------- single avg pool (abs output), division-free ----------------
template <int R, int TH>
__global__ __launch_bounds__(256, 4) void avg_abs_pool(const float* __restrict__ src,
                                                       float* __restrict__ dst) {
    constexpr int TILES = HH / TH;
    __shared__ float ls[TH * PADW];
    const int plane = blockIdx.x / TILES;
    const int tile  = blockIdx.x % TILES;
    const int i0    = tile * TH;
    const size_t pbase = (size_t)plane * SS;
    const float* sp = src + pbase;
    const int t = threadIdx.x;

    auto ld = [&](int gi) -> float2 {
        if ((unsigned)gi < (unsigned)HH) return ((const float2*)(sp + (size_t)gi * WW))[t];
        return make_float2(0.f, 0.f);
    };
    float2 acc = make_float2(0.f, 0.f);
    #pragma unroll
    for (int k = -R; k <= R; ++k) { float2 v = ld(i0 + k); acc.x += v.x; acc.y += v.y; }
    const int ca = swz(2 * t);
    ls[ca] = acc.x; ls[ca + 1] = acc.y;
    #pragma unroll
    for (int oi = 1; oi < TH; ++oi) {
        float2 a = ld(i0 + oi + R), s = ld(i0 + oi - R - 1);
        acc.x += a.x - s.x; acc.y += a.y - s.y;
        ls[oi * PADW + ca] = acc.x; ls[oi * PADW + ca + 1] = acc.y;
    }
    __syncthreads();

    for (int s = t; s < TH * 64; s += 256) {
        int rr = s >> 6, j0 = (s & 63) << 3;
        int i = i0 + rr;
        int ch = min(i + R, HH - 1) - max(i - R, 0) + 1;
        float invch = invsmall<R>(ch);
        const float* row = &ls[rr * PADW];
        int lo = max(j0 - R, 0), hi = min(j0 + R, WW - 1);
        float racc = 0.f;
        for (int jj = lo; jj <= hi; ++jj) racc += row[swz(jj)];
        float ov[8];
        #pragma unroll
        for (int d = 0; d < 8; ++d) {
            if (d > 0) {
                int add = j0 + d + R, sub = j0 + d - R - 1;
                if (add < WW) racc += row[swz(add)];
                if (sub >= 0) racc -= row[swz(sub)];
            }
            int j = j0 + d;
            int cw = min(j + R, WW - 1) - max(j - R, 0) + 1;
            ov[d] = fabsf(racc * (invch * invsmall<R>(cw)));
        }
        float4* d4 = (float4*)&dst[pbase + (size_t)i * WW + j0];
        d4[0] = make_float4(ov[0], ov[1], ov[2], ov[3]);
        d4[1] = make_float4(ov[4], ov[5], ov[6], ov[7]);
    }
}

// ---------------- dual-input avg pool + gn1 epilogue (EPI=1) ----------------
// out = (|e1|*chcw - racc2)/(|racc1 - racc2| + 1e-4*chcw)    [division-free]
// Phase-split over ONE LDS buffer: s1 horizontal sums held in regs (keep1).
template <int R, int EPI, int TH>
__global__ __launch_bounds__(256, 4) void davg_pool(const float* __restrict__ s1,
                                                    const float* __restrict__ s2,
                                                    const float* __restrict__ e1,
                                                    const float* __restrict__ e2,
                                                    float* __restrict__ dst) {
    constexpr int TILES = HH / TH;
    constexpr int NS = (TH * 64) / 256;
    __shared__ float lbuf[TH * PADW];
    const int plane = blockIdx.x / TILES;
    const int tile  = blockIdx.x % TILES;
    const int i0    = tile * TH;
    const size_t pbase = (size_t)plane * SS;
    const int t = threadIdx.x;
    const int ca = swz(2 * t);

    auto vert = [&](const float* sp) {
        auto ld = [&](int gi) -> float2 {
            if ((unsigned)gi < (unsigned)HH) return ((const float2*)(sp + (size_t)gi * WW))[t];
            return make_float2(0.f, 0.f);
        };
        float2 acc = make_float2(0.f, 0.f);
        #pragma unroll
        for (int k = -R; k <= R; ++k) { float2 v = ld(i0 + k); acc.x += v.x; acc.y += v.y; }
        lbuf[ca] = acc.x; lbuf[ca + 1] = acc.y;
        #pragma unroll
        for (int oi = 1; oi < TH; ++oi) {
            float2 a = ld(i0 + oi + R), s = ld(i0 + oi - R - 1);
            acc.x += a.x - s.x; acc.y += a.y - s.y;
            lbuf[oi * PADW + ca] = acc.x; lbuf[oi * PADW + ca + 1] = acc.y;
        }
    };

    float keep1[NS * 8];                           // raw horizontal sums of s1

    // ---- phase A: s1 ----
    vert(s1 + pbase);
    __syncthreads();
    #pragma unroll
    for (int si = 0; si < NS; ++si) {
        int s = si * 256 + t;
        int rr = s >> 6, j0 = (s & 63) << 3;
        const float* row = &lbuf[rr * PADW];
        int lo = max(j0 - R, 0), hi = min(j0 + R, WW - 1);
        float racc = 0.f;
        for (int jj = lo; jj <= hi; ++jj) racc += row[swz(jj)];
        #pragma unroll
        for (int d = 0; d < 8; ++d) {
            if (d > 0) {
                int add = j0 + d + R, sub = j0 + d - R - 1;
                if (add < WW) racc += row[swz(add)];
                if (sub >= 0) racc -= row[swz(sub)];
            }
            keep1[si * 8 + d] = racc;
        }
    }
    __syncthreads();

    // ---- phase B: s2 + epilogue ----
    vert(s2 + pbase);
    __syncthreads();
    #pragma unroll
    for (int si = 0; si < NS; ++si) {
        int s = si * 256 + t;
        int rr = s >> 6, j0 = (s & 63) << 3;
        int i = i0 + rr;
        int ch = min(i + R, HH - 1) - max(i - R, 0) + 1;
        const float* row = &lbuf[rr * PADW];
        size_t rowbase = pbase + (size_t)i * WW + j0;

        float e1v[8], e2v[8];
        {
            float4 a0 = ((const float4*)(e1 + rowbase))[0];
            float4 a1q = ((const float4*)(e1 + rowbase))[1];
            e1v[0]=a0.x; e1v[1]=a0.y; e1v[2]=a0.z; e1v[3]=a0.w;
            e1v[4]=a1q.x; e1v[5]=a1q.y; e1v[6]=a1q.z; e1v[7]=a1q.w;
        }
        if (EPI == 2) {
            float4 b0 = ((const float4*)(e2 + rowbase))[0];
            float4 b1q = ((const float4*)(e2 + rowbase))[1];
            e2v[0]=b0.x; e2v[1]=b0.y; e2v[2]=b0.z; e2v[3]=b0.w;
            e2v[4]=b1q.x; e2v[5]=b1q.y; e2v[6]=b1q.z; e2v[7]=b1q.w;
        }

        int lo = max(j0 - R, 0), hi = min(j0 + R, WW - 1);
        float racc2 = 0.f;
        for (int jj = lo; jj <= hi; ++jj) racc2 += row[swz(jj)];
        float ov[8];
        #pragma unroll
        for (int d = 0; d < 8; ++d) {
            if (d > 0) {
                int add = j0 + d + R, sub = j0 + d - R - 1;
                if (add < WW) racc2 += row[swz(add)];
                if (sub >= 0) racc2 -= row[swz(sub)];
            }
            int j = j0 + d;
            int cw = min(j + R, WW - 1) - max(j - R, 0) + 1;
            float chcw = (float)(ch * cw);
            float r1 = keep1[si * 8 + d];
            float den = fabsf(r1 - racc2) + 1e-4f * chcw;
            if (EPI == 1) {
                ov[d] = (fabsf(e1v[d]) * chcw - racc2) / den;
            } else {
                ov[d] = ((e1v[d] * chcw - racc2) / den + 0.01f) * e2v[d];
            }
        }
        float4* d4 = (float4*)&dst[rowbase];
        d4[0] = make_float4(ov[0], ov[1], ov[2], ov[3]);
        d4[1] = make_float4(ov[4], ov[5], ov[6], ov[7]);
    }
}

// ---------------- final: dual avg + map + paired reduction ----------------
// Block handles planes (pR, pR+16) = (R, L) for one tile.
// mapX = ((e1*chcw - racc2)/(|racc1-racc2| + 1e-4*chcw) + 0.01) * e2
// Factorized: fR = mapR*exp(-10*mapR) kept in regs; acc += fR*exp(-10*mapL).
// keep1 scoped per half (live range closes) -> peak array regs = 64 < cap 168
// (launch_bounds(256,3)). No dst write; one atomicAdd per block.
template <int R, int TH>
__global__ __launch_bounds__(256, 3) void davg_final(const float* __restrict__ s1,
                                                     const float* __restrict__ s2,
                                                     const float* __restrict__ e1,
                                                     const float* __restrict__ e2,
                                                     float* __restrict__ out, float scale) {
    constexpr int TILES = HH / TH;
    constexpr int NS = (TH * 64) / 256;
    __shared__ float lbuf[TH * PADW];
    __shared__ float red[4];
    const int pairidx = blockIdx.x / TILES;
    const int tile    = blockIdx.x % TILES;
    const int i0      = tile * TH;
    const int planeR  = pairidx + ((pairidx >> 4) << 4);   // 0..15->0..15; 16..31->32..47
    const int t = threadIdx.x;
    const int ca = swz(2 * t);

    auto vert = [&](const float* sp) {
        auto ld = [&](int gi) -> float2 {
            if ((unsigned)gi < (unsigned)HH) return ((const float2*)(sp + (size_t)gi * WW))[t];
            return make_float2(0.f, 0.f);
        };
        float2 a = make_float2(0.f, 0.f);
        #pragma unroll
        for (int k = -R; k <= R; ++k) { float2 v = ld(i0 + k); a.x += v.x; a.y += v.y; }
        lbuf[ca] = a.x; lbuf[ca + 1] = a.y;
        #pragma unroll
        for (int oi = 1; oi < TH; ++oi) {
            float2 p = ld(i0 + oi + R), q = ld(i0 + oi - R - 1);
            a.x += p.x - q.x; a.y += p.y - q.y;
            lbuf[oi * PADW + ca] = a.x; lbuf[oi * PADW + ca + 1] = a.y;
        }
    };

    float fR[NS * 8];
    float acc = 0.f;

    #pragma unroll
    for (int half = 0; half < 2; ++half) {
        const size_t pbase = (size_t)(planeR + half * 16) * SS;
        float keep1[NS * 8];                       // scoped: dies at end of half

        // phase A: s1 (max7) column sums -> horizontal raw sums
        vert(s1 + pbase);
        __syncthreads();
        #pragma unroll
        for (int si = 0; si < NS; ++si) {
            int s = si * 256 + t;
            int rr = s >> 6, j0 = (s & 63) << 3;
            const float* row = &lbuf[rr * PADW];
            int lo = max(j0 - R, 0), hi = min(j0 + R, WW - 1);
            float racc = 0.f;
            for (int jj = lo; jj <= hi; ++jj) racc += row[swz(jj)];
            #pragma unroll
            for (int d = 0; d < 8; ++d) {
                if (d > 0) {
                    int add = j0 + d + R, sub = j0 + d - R - 1;
                    if (add < WW) racc += row[swz(add)];
                    if (sub >= 0) racc -= row[swz(sub)];
                }
                keep1[si * 8 + d] = racc;
            }
        }
        __syncthreads();

        // phase B: s2 (min7) + map epilogue
        vert(s2 + pbase);
        __syncthreads();
        #pragma unroll
        for (int si = 0; si < NS; ++si) {
            int s = si * 256 + t;
            int rr = s >> 6, j0 = (s & 63) << 3;
            int i = i0 + rr;
            int ch = min(i + R, HH - 1) - max(i - R, 0) + 1;
            const float* row = &lbuf[rr * PADW];
            size_t rowbase = pbase + (size_t)i * WW + j0;

            float e1v[8], e2v[8];
            {
                float4 a0 = ((const float4*)(e1 + rowbase))[0];
                float4 a1q = ((const float4*)(e1 + rowbase))[1];
                e1v[0]=a0.x; e1v[1]=a0.y; e1v[2]=a0.z; e1v[3]=a0.w;
                e1v[4]=a1q.x; e1v[5]=a1q.y; e1v[6]=a1q.z; e1v[7]=a1q.w;
                float4 b0 = ((const float4*)(e2 + rowbase))[0];
                float4 b1q = ((const float4*)(e2 + rowbase))[1];
                e2v[0]=b0.x; e2v[1]=b0.y; e2v[2]=b0.z; e2v[3]=b0.w;
                e2v[4]=b1q.x; e2v[5]=b1q.y; e2v[6]=b1q.z; e2v[7]=b1q.w;
            }

            int lo = max(j0 - R, 0), hi = min(j0 + R, WW - 1);
            float racc2 = 0.f;
            for (int jj = lo; jj <= hi; ++jj) racc2 += row[swz(jj)];
            #pragma unroll
            for (int d = 0; d < 8; ++d) {
                if (d > 0) {
                    int add = j0 + d + R, sub = j0 + d - R - 1;
                    if (add < WW) racc2 += row[swz(add)];
                    if (sub >= 0) racc2 -= row[swz(sub)];
                }
                int j = j0 + d;
                int cw = min(j + R, WW - 1) - max(j - R, 0) + 1;
                float chcw = (float)(ch * cw);
                float r1 = keep1[si * 8 + d];
                float den = fabsf(r1 - racc2) + 1e-4f * chcw;
                float mp = ((e1v[d] * chcw - racc2) / den + 0.01f) * e2v[d];
                if (half == 0) {
                    fR[si * 8 + d] = mp * expf(-10.f * mp);
                } else {
                    acc += fR[si * 8 + d] * expf(-10.f * mp);
                }
            }
        }
        __syncthreads();                           // before lbuf reuse
    }

    #pragma unroll
    for (int off = 32; off; off >>= 1) acc += __shfl_down(acc, off);
    int lane = t & 63, wv = t >> 6;
    if (lane == 0) red[wv] = acc;
    __syncthreads();
    if (t == 0) atomicAdd(out, (red[0] + red[1] + red[2] + red[3]) * scale);
}

// ---------------- host orchestration ----------------
// Round-7 champion structure; final stage fused (davg3+map+pair+reduce).
// G=g -> dual9(G->A,B) -> davg8(A,B,G->C=gn1) -> avg_abs(G->A=go)
// -> dual7(A->B=max7, G=min7) -> davg_final(B,G,A,C -> atomicAdd out).

extern "C" void kernel_launch(void* const* d_in, const int* in_sizes, int n_in,
                              void* d_out, int out_size, void* d_ws, size_t ws_size,
                              hipStream_t stream) {
    const float* Rrgb = (const float*)d_in[0];
    const float* Lrgb = (const float*)d_in[1];
    float* out = (float*)d_out;
    float* w = (float*)d_ws;
    const float scale = 1.f / (float)P16N;
    const int gradblk = (P16N / 4 + 255) / 256;

    hipMemsetAsync(out, 0, sizeof(float) * (size_t)out_size, stream);

    const size_t stack64 = (size_t)64 * SS;
    if (ws_size >= 4 * stack64 * sizeof(float)) {
        // 4 buffers of 64 planes: layout [0..16)=Rgx [16..32)=Lgx [32..48)=Rgy [48..64)=Lgy
        float* G = w;
        float* A = G + stack64;
        float* B = A + stack64;
        float* C = B + stack64;
        grad_both<<<gradblk, 256, 0, stream>>>(Rrgb, G, 0, 32, 2);
        grad_both<<<gradblk, 256, 0, stream>>>(Lrgb, G, 16, 48, 2);
        int gp = 64 * (HH / 16);
        dual_pool<true, 4, 16><<<gp, 256, 0, stream>>>(G, A, B);          // A=max9|g|, B=min9|g|
        davg_pool<8, 1, 16><<<gp, 256, 0, stream>>>(A, B, G, nullptr, C); // C=gn1
        avg_abs_pool<2, 16><<<gp, 256, 0, stream>>>(G, A);                // A=go (G dead)
        dual_pool<false, 3, 16><<<gp, 256, 0, stream>>>(A, B, G);         // B=max7, G=min7
        int fp = 32 * (HH / 16);
        davg_final<3, 16><<<fp, 256, 0, stream>>>(B, G, A, C, out, scale);
    } else {
        // fallback: 4 buffers of 32 planes (128 MiB), one direction at a time
        const size_t stack32 = (size_t)32 * SS;
        float* G = w;
        float* A = G + stack32;
        float* B = A + stack32;
        float* C = B + stack32;
        for (int dir = 0; dir < 2; ++dir) {
            grad_both<<<gradblk, 256, 0, stream>>>(Rrgb, G, 0, 0, dir);
            grad_both<<<gradblk, 256, 0, stream>>>(Lrgb, G, 16, 16, dir);
            int gp = 32 * (HH / 16);
            dual_pool<true, 4, 16><<<gp, 256, 0, stream>>>(G, A, B);
            davg_pool<8, 1, 16><<<gp, 256, 0, stream>>>(A, B, G, nullptr, C);
            avg_abs_pool<2, 16><<<gp, 256, 0, stream>>>(G, A);
            dual_pool<false, 3, 16><<<gp, 256, 0, stream>>>(A, B, G);
            int fp = 16 * (HH / 16);
            davg_final<3, 16><<<fp, 256, 0, stream>>>(B, G, A, C, out, scale);
        }
    }
}

// Round 9
// 373.756 us; speedup vs baseline: 1.2901x; 1.2901x over previous
//
#include <hip/hip_runtime.h>

#define HH 512
#define WW 512
#define SS (HH * WW)          // elements per plane (2^18)
#define P16N (16 * SS)        // 16 planes (2^22)
#define PADW 576              // skewed LDS row: addr(j) = j + (j>>3)

constexpr float FINF = 3.402823466e38f;

__device__ __forceinline__ int swz(int j) { return j + (j >> 3); }

__device__ __forceinline__ float gray1(float r, float g, float b) {
    return 0.299f * r + 0.587f * g + 0.114f * b;
}

// inverse of small integer c in [R+1, 2R+1] without v_div (cmp+cndmask chain)
template <int R>
__device__ __forceinline__ float invsmall(int c) {
    float r = 1.f / (float)(2 * R + 1);
    #pragma unroll
    for (int v = R + 1; v < 2 * R + 1; ++v)
        if (c == v) r = 1.f / (float)v;      // compile-time constants
    return r;
}

// ---------------- grad (gray fused, both dirs, 4 px/thread) ----------------
__global__ __launch_bounds__(256) void grad_both(const float* __restrict__ rgb,
                                                 float* __restrict__ dst,
                                                 int gxp0, int gyp0, int dirsel) {
    int sp = blockIdx.x * 256 + threadIdx.x;
    int idx = sp << 2;                             // [0, P16N)
    int img = idx >> 18;
    int pix = idx & (SS - 1);
    int i = pix >> 9, j0 = pix & (WW - 1);
    const float* p0 = rgb + (size_t)img * 3 * SS + pix;

    float4 r = *(const float4*)p0;
    float4 g = *(const float4*)(p0 + SS);
    float4 b = *(const float4*)(p0 + 2 * SS);
    float4 gy4 = make_float4(gray1(r.x, g.x, b.x), gray1(r.y, g.y, b.y),
                             gray1(r.z, g.z, b.z), gray1(r.w, g.w, b.w));
    if (dirsel != 1) {
        float grs = 0.f;
        if (j0 + 4 < WW) grs = gray1(p0[4], p0[SS + 4], p0[2 * SS + 4]);
        float4 gx = make_float4(gy4.x - gy4.y, gy4.y - gy4.z, gy4.z - gy4.w, gy4.w - grs);
        *(float4*)(dst + (size_t)(gxp0 + img) * SS + pix) = gx;
    }
    if (dirsel != 0) {
        float4 gd = make_float4(0.f, 0.f, 0.f, 0.f);
        if (i < HH - 1) {
            float4 r2 = *(const float4*)(p0 + WW);
            float4 g2 = *(const float4*)(p0 + SS + WW);
            float4 b2 = *(const float4*)(p0 + 2 * SS + WW);
            gd = make_float4(gray1(r2.x, g2.x, b2.x), gray1(r2.y, g2.y, b2.y),
                             gray1(r2.z, g2.z, b2.z), gray1(r2.w, g2.w, b2.w));
        }
        float4 gy = make_float4(gy4.x - gd.x, gy4.y - gd.y, gy4.z - gd.z, gy4.w - gd.w);
        *(float4*)(dst + (size_t)(gyp0 + img) * SS + pix) = gy;
    }
}

// ---------------- dual max+min pool (column-first, skewed LDS) ----------------
// SINGLE ring buffer rb[W]; exact wrap-counted validity mask (compile-time
// except i0). Phase-split over ONE LDS buffer (36864 B -> 4 blocks/CU):
// vertical max -> LDS, min -> regs; hmax -> dmax; reload; hmin -> dmin.
template <bool PREABS, int R, int TH>
__global__ __launch_bounds__(256, 4) void dual_pool(const float* __restrict__ src,
                                                    float* __restrict__ dmax,
                                                    float* __restrict__ dmin) {
    constexpr int TILES = HH / TH;
    constexpr int W = 2 * R + 1;
    constexpr int NS = (TH * 64) / 256;
    __shared__ float lbuf[TH * PADW];

    const int plane = blockIdx.x / TILES;
    const int tile  = blockIdx.x % TILES;
    const int i0    = tile * TH;
    const size_t pbase = (size_t)plane * SS;
    const float* sp = src + pbase;
    const int t = threadIdx.x;
    const int ca = swz(2 * t);                     // ca+1 == swz(2t+1)

    float2 rb[W];
    float2 keepmn[TH];
    auto ld = [&](int gi) -> float2 {
        float2 u = ((const float2*)(sp + (size_t)gi * WW))[t];
        if (PREABS) { u.x = fabsf(u.x); u.y = fabsf(u.y); }
        return u;
    };
    #pragma unroll
    for (int k = 0; k < W; ++k)
        if ((unsigned)(i0 - R + k) < (unsigned)HH) rb[k] = ld(i0 - R + k);
    #pragma unroll
    for (int oi = 0; oi < TH; ++oi) {
        if (oi > 0) {
            if ((unsigned)(i0 + oi + R) < (unsigned)HH) rb[(oi - 1) % W] = ld(i0 + oi + R);
        }
        float2 mx = make_float2(-FINF, -FINF), mn = make_float2(FINF, FINF);
        #pragma unroll
        for (int k = 0; k < W; ++k) {
            int wrap = (oi > k) ? ((oi - 1 - k) / W + 1) : 0;   // compile-time
            int ro = k - R + wrap * W;                          // exact row in slot k
            if ((unsigned)(i0 + ro) < (unsigned)HH) {           // block-uniform branch
                mx.x = fmaxf(mx.x, rb[k].x); mx.y = fmaxf(mx.y, rb[k].y);
                mn.x = fminf(mn.x, rb[k].x); mn.y = fminf(mn.y, rb[k].y);
            }
        }
        lbuf[oi * PADW + ca] = mx.x; lbuf[oi * PADW + ca + 1] = mx.y;
        keepmn[oi] = mn;
    }
    __syncthreads();

    // horizontal max -> dmax
    #pragma unroll
    for (int si = 0; si < NS; ++si) {
        int s = si * 256 + t;
        int rr = s >> 6, j0 = (s & 63) << 3;
        const float* rx = &lbuf[rr * PADW];
        float vx[2 * R + 8];
        #pragma unroll
        for (int k = 0; k < 2 * R + 8; ++k) {
            int jj = j0 - R + k;
            bool ok = (unsigned)jj < (unsigned)WW;
            int jc = swz(min(max(jj, 0), WW - 1));
            vx[k] = ok ? rx[jc] : -FINF;
        }
        float ox[8];
        #pragma unroll
        for (int d = 0; d < 8; ++d) {
            float mx = vx[d];
            #pragma unroll
            for (int k = 1; k <= 2 * R; ++k) mx = fmaxf(mx, vx[d + k]);
            ox[d] = mx;
        }
        size_t o = pbase + (size_t)(i0 + rr) * WW + j0;
        ((float4*)&dmax[o])[0] = make_float4(ox[0], ox[1], ox[2], ox[3]);
        ((float4*)&dmax[o])[1] = make_float4(ox[4], ox[5], ox[6], ox[7]);
    }
    __syncthreads();

    // swap in the vertical-min column results
    #pragma unroll
    for (int oi = 0; oi < TH; ++oi) {
        lbuf[oi * PADW + ca] = keepmn[oi].x;
        lbuf[oi * PADW + ca + 1] = keepmn[oi].y;
    }
    __syncthreads();

    // horizontal min -> dmin
    #pragma unroll
    for (int si = 0; si < NS; ++si) {
        int s = si * 256 + t;
        int rr = s >> 6, j0 = (s & 63) << 3;
        const float* rn = &lbuf[rr * PADW];
        float vn[2 * R + 8];
        #pragma unroll
        for (int k = 0; k < 2 * R + 8; ++k) {
            int jj = j0 - R + k;
            bool ok = (unsigned)jj < (unsigned)WW;
            int jc = swz(min(max(jj, 0), WW - 1));
            vn[k] = ok ? rn[jc] : FINF;
        }
        float on[8];
        #pragma unroll
        for (int d = 0; d < 8; ++d) {
            float mn = vn[d];
            #pragma unroll
            for (int k = 1; k <= 2 * R; ++k) mn = fminf(mn, vn[d + k]);
            on[d] = mn;
        }
        size_t o = pbase + (size_t)(i0 + rr) * WW + j0;
        ((float4*)&dmin[o])[0] = make_float4(on[0], on[1], on[2], on[3]);
        ((float4*)&dmin[o])[1] = make_float4(on[4], on[5], on[6], on[7]);
    }
}

// ---------------- single avg pool (abs output), division-free ----------------
template <int R, int TH>
__global__ __launch_bounds__(256, 4) void avg_abs_pool(const float* __restrict__ src,
                                                       float* __restrict__ dst) {
    constexpr int TILES = HH / TH;
    __shared__ float ls[TH * PADW];
    const int plane = blockIdx.x / TILES;
    const int tile  = blockIdx.x % TILES;
    const int i0    = tile * TH;
    const size_t pbase = (size_t)plane * SS;
    const float* sp = src + pbase;
    const int t = threadIdx.x;

    auto ld = [&](int gi) -> float2 {
        if ((unsigned)gi < (unsigned)HH) return ((const float2*)(sp + (size_t)gi * WW))[t];
        return make_float2(0.f, 0.f);
    };
    float2 acc = make_float2(0.f, 0.f);
    #pragma unroll
    for (int k = -R; k <= R; ++k) { float2 v = ld(i0 + k); acc.x += v.x; acc.y += v.y; }
    const int ca = swz(2 * t);
    ls[ca] = acc.x; ls[ca + 1] = acc.y;
    #pragma unroll
    for (int oi = 1; oi < TH; ++oi) {
        float2 a = ld(i0 + oi + R), s = ld(i0 + oi - R - 1);
        acc.x += a.x - s.x; acc.y += a.y - s.y;
        ls[oi * PADW + ca] = acc.x; ls[oi * PADW + ca + 1] = acc.y;
    }
    __syncthreads();

    for (int s = t; s < TH * 64; s += 256) {
        int rr = s >> 6, j0 = (s & 63) << 3;
        int i = i0 + rr;
        int ch = min(i + R, HH - 1) - max(i - R, 0) + 1;
        float invch = invsmall<R>(ch);
        const float* row = &ls[rr * PADW];
        int lo = max(j0 - R, 0), hi = min(j0 + R, WW - 1);
        float racc = 0.f;
        for (int jj = lo; jj <= hi; ++jj) racc += row[swz(jj)];
        float ov[8];
        #pragma unroll
        for (int d = 0; d < 8; ++d) {
            if (d > 0) {
                int add = j0 + d + R, sub = j0 + d - R - 1;
                if (add < WW) racc += row[swz(add)];
                if (sub >= 0) racc -= row[swz(sub)];
            }
            int j = j0 + d;
            int cw = min(j + R, WW - 1) - max(j - R, 0) + 1;
            ov[d] = fabsf(racc * (invch * invsmall<R>(cw)));
        }
        float4* d4 = (float4*)&dst[pbase + (size_t)i * WW + j0];
        d4[0] = make_float4(ov[0], ov[1], ov[2], ov[3]);
        d4[1] = make_float4(ov[4], ov[5], ov[6], ov[7]);
    }
}

// ---------------- dual-input avg pool + gn1 epilogue (EPI=1) ----------------
// out = (|e1|*chcw - racc2)/(|racc1 - racc2| + 1e-4*chcw)    [division-free]
// Phase-split over ONE LDS buffer: s1 horizontal sums held in regs (keep1).
template <int R, int EPI, int TH>
__global__ __launch_bounds__(256, 4) void davg_pool(const float* __restrict__ s1,
                                                    const float* __restrict__ s2,
                                                    const float* __restrict__ e1,
                                                    const float* __restrict__ e2,
                                                    float* __restrict__ dst) {
    constexpr int TILES = HH / TH;
    constexpr int NS = (TH * 64) / 256;
    __shared__ float lbuf[TH * PADW];
    const int plane = blockIdx.x / TILES;
    const int tile  = blockIdx.x % TILES;
    const int i0    = tile * TH;
    const size_t pbase = (size_t)plane * SS;
    const int t = threadIdx.x;
    const int ca = swz(2 * t);

    auto vert = [&](const float* sp) {
        auto ld = [&](int gi) -> float2 {
            if ((unsigned)gi < (unsigned)HH) return ((const float2*)(sp + (size_t)gi * WW))[t];
            return make_float2(0.f, 0.f);
        };
        float2 acc = make_float2(0.f, 0.f);
        #pragma unroll
        for (int k = -R; k <= R; ++k) { float2 v = ld(i0 + k); acc.x += v.x; acc.y += v.y; }
        lbuf[ca] = acc.x; lbuf[ca + 1] = acc.y;
        #pragma unroll
        for (int oi = 1; oi < TH; ++oi) {
            float2 a = ld(i0 + oi + R), s = ld(i0 + oi - R - 1);
            acc.x += a.x - s.x; acc.y += a.y - s.y;
            lbuf[oi * PADW + ca] = acc.x; lbuf[oi * PADW + ca + 1] = acc.y;
        }
    };

    float keep1[NS * 8];                           // raw horizontal sums of s1

    // ---- phase A: s1 ----
    vert(s1 + pbase);
    __syncthreads();
    #pragma unroll
    for (int si = 0; si < NS; ++si) {
        int s = si * 256 + t;
        int rr = s >> 6, j0 = (s & 63) << 3;
        const float* row = &lbuf[rr * PADW];
        int lo = max(j0 - R, 0), hi = min(j0 + R, WW - 1);
        float racc = 0.f;
        for (int jj = lo; jj <= hi; ++jj) racc += row[swz(jj)];
        #pragma unroll
        for (int d = 0; d < 8; ++d) {
            if (d > 0) {
                int add = j0 + d + R, sub = j0 + d - R - 1;
                if (add < WW) racc += row[swz(add)];
                if (sub >= 0) racc -= row[swz(sub)];
            }
            keep1[si * 8 + d] = racc;
        }
    }
    __syncthreads();

    // ---- phase B: s2 + epilogue ----
    vert(s2 + pbase);
    __syncthreads();
    #pragma unroll
    for (int si = 0; si < NS; ++si) {
        int s = si * 256 + t;
        int rr = s >> 6, j0 = (s & 63) << 3;
        int i = i0 + rr;
        int ch = min(i + R, HH - 1) - max(i - R, 0) + 1;
        const float* row = &lbuf[rr * PADW];
        size_t rowbase = pbase + (size_t)i * WW + j0;

        float e1v[8], e2v[8];
        {
            float4 a0 = ((const float4*)(e1 + rowbase))[0];
            float4 a1q = ((const float4*)(e1 + rowbase))[1];
            e1v[0]=a0.x; e1v[1]=a0.y; e1v[2]=a0.z; e1v[3]=a0.w;
            e1v[4]=a1q.x; e1v[5]=a1q.y; e1v[6]=a1q.z; e1v[7]=a1q.w;
        }
        if (EPI == 2) {
            float4 b0 = ((const float4*)(e2 + rowbase))[0];
            float4 b1q = ((const float4*)(e2 + rowbase))[1];
            e2v[0]=b0.x; e2v[1]=b0.y; e2v[2]=b0.z; e2v[3]=b0.w;
            e2v[4]=b1q.x; e2v[5]=b1q.y; e2v[6]=b1q.z; e2v[7]=b1q.w;
        }

        int lo = max(j0 - R, 0), hi = min(j0 + R, WW - 1);
        float racc2 = 0.f;
        for (int jj = lo; jj <= hi; ++jj) racc2 += row[swz(jj)];
        float ov[8];
        #pragma unroll
        for (int d = 0; d < 8; ++d) {
            if (d > 0) {
                int add = j0 + d + R, sub = j0 + d - R - 1;
                if (add < WW) racc2 += row[swz(add)];
                if (sub >= 0) racc2 -= row[swz(sub)];
            }
            int j = j0 + d;
            int cw = min(j + R, WW - 1) - max(j - R, 0) + 1;
            float chcw = (float)(ch * cw);
            float r1 = keep1[si * 8 + d];
            float den = fabsf(r1 - racc2) + 1e-4f * chcw;
            if (EPI == 1) {
                ov[d] = (fabsf(e1v[d]) * chcw - racc2) / den;
            } else {
                ov[d] = ((e1v[d] * chcw - racc2) / den + 0.01f) * e2v[d];
            }
        }
        float4* d4 = (float4*)&dst[rowbase];
        d4[0] = make_float4(ov[0], ov[1], ov[2], ov[3]);
        d4[1] = make_float4(ov[4], ov[5], ov[6], ov[7]);
    }
}

// ---------------- paired final: dual avg + map + reduction, LDS-exchange ----------------
// 512 threads: lower half (t<256) = plane R, upper half = plane L (=R+16).
// Each half runs the proven davg_pool phase structure on its own lbuf half
// (per-thread state = ONE keep1[32], the no-spill profile). Per 8-col slice,
// the L-half posts exp(-10*mapL) through an 8KB LDS exchange (thread-major,
// conflict-free) and the R-half accumulates mapR*exp(-10*mapR)*exch.
// LDS = 73728 + 8192 = 81920 B -> 2 blocks/CU (16 waves).
template <int R, int TH>
__global__ __launch_bounds__(512, 4) void davg_final2(const float* __restrict__ s1,
                                                      const float* __restrict__ s2,
                                                      const float* __restrict__ e1,
                                                      const float* __restrict__ e2,
                                                      float* __restrict__ out, float scale) {
    constexpr int TILES = HH / TH;
    constexpr int NS = (TH * 64) / 256;            // 4 slices per half
    __shared__ float lbuf[2 * TH * PADW];          // 73728 B
    __shared__ float exch[2048];                   // 8192 B (also final red buffer)

    const int t    = threadIdx.x;
    const int half = t >> 8;                       // 0 = R-plane, 1 = L-plane
    const int tl   = t & 255;
    const int pairidx = blockIdx.x / TILES;
    const int tile    = blockIdx.x % TILES;
    const int i0      = tile * TH;
    const int planeR  = pairidx + ((pairidx >> 4) << 4);   // 0..15->0..15; 16..31->32..47
    const size_t pbase = (size_t)(planeR + half * 16) * SS;
    float* myl = lbuf + half * (TH * PADW);
    const int ca = swz(2 * tl);

    auto vert = [&](const float* sp) {
        auto ld = [&](int gi) -> float2 {
            if ((unsigned)gi < (unsigned)HH) return ((const float2*)(sp + (size_t)gi * WW))[tl];
            return make_float2(0.f, 0.f);
        };
        float2 a = make_float2(0.f, 0.f);
        #pragma unroll
        for (int k = -R; k <= R; ++k) { float2 v = ld(i0 + k); a.x += v.x; a.y += v.y; }
        myl[ca] = a.x; myl[ca + 1] = a.y;
        #pragma unroll
        for (int oi = 1; oi < TH; ++oi) {
            float2 p = ld(i0 + oi + R), q = ld(i0 + oi - R - 1);
            a.x += p.x - q.x; a.y += p.y - q.y;
            myl[oi * PADW + ca] = a.x; myl[oi * PADW + ca + 1] = a.y;
        }
    };

    float keep1[NS * 8];                           // the ONLY per-thread array

    // phase A: s1 (max7) -> keep1
    vert(s1 + pbase);
    __syncthreads();
    #pragma unroll
    for (int si = 0; si < NS; ++si) {
        int s = si * 256 + tl;
        int rr = s >> 6, j0 = (s & 63) << 3;
        const float* row = &myl[rr * PADW];
        int lo = max(j0 - R, 0), hi = min(j0 + R, WW - 1);
        float racc = 0.f;
        for (int jj = lo; jj <= hi; ++jj) racc += row[swz(jj)];
        #pragma unroll
        for (int d = 0; d < 8; ++d) {
            if (d > 0) {
                int add = j0 + d + R, sub = j0 + d - R - 1;
                if (add < WW) racc += row[swz(add)];
                if (sub >= 0) racc -= row[swz(sub)];
            }
            keep1[si * 8 + d] = racc;
        }
    }
    __syncthreads();

    // phase B: s2 (min7) + map + per-slice exchange
    vert(s2 + pbase);
    __syncthreads();
    float acc = 0.f;
    #pragma unroll
    for (int si = 0; si < NS; ++si) {
        int s = si * 256 + tl;
        int rr = s >> 6, j0 = (s & 63) << 3;
        int i = i0 + rr;
        int ch = min(i + R, HH - 1) - max(i - R, 0) + 1;
        const float* row = &myl[rr * PADW];
        size_t rowbase = pbase + (size_t)i * WW + j0;

        float e1v[8], e2v[8];
        {
            float4 a0 = ((const float4*)(e1 + rowbase))[0];
            float4 a1q = ((const float4*)(e1 + rowbase))[1];
            e1v[0]=a0.x; e1v[1]=a0.y; e1v[2]=a0.z; e1v[3]=a0.w;
            e1v[4]=a1q.x; e1v[5]=a1q.y; e1v[6]=a1q.z; e1v[7]=a1q.w;
            float4 b0 = ((const float4*)(e2 + rowbase))[0];
            float4 b1q = ((const float4*)(e2 + rowbase))[1];
            e2v[0]=b0.x; e2v[1]=b0.y; e2v[2]=b0.z; e2v[3]=b0.w;
            e2v[4]=b1q.x; e2v[5]=b1q.y; e2v[6]=b1q.z; e2v[7]=b1q.w;
        }

        int lo = max(j0 - R, 0), hi = min(j0 + R, WW - 1);
        float racc2 = 0.f;
        for (int jj = lo; jj <= hi; ++jj) racc2 += row[swz(jj)];
        float mp[8];
        #pragma unroll
        for (int d = 0; d < 8; ++d) {
            if (d > 0) {
                int add = j0 + d + R, sub = j0 + d - R - 1;
                if (add < WW) racc2 += row[swz(add)];
                if (sub >= 0) racc2 -= row[swz(sub)];
            }
            int j = j0 + d;
            int cw = min(j + R, WW - 1) - max(j - R, 0) + 1;
            float chcw = (float)(ch * cw);
            float den = fabsf(keep1[si * 8 + d] - racc2) + 1e-4f * chcw;
            mp[d] = ((e1v[d] * chcw - racc2) / den + 0.01f) * e2v[d];
        }
        if (half == 1) {                           // wave-uniform branch
            #pragma unroll
            for (int d = 0; d < 8; ++d) exch[d * 256 + tl] = expf(-10.f * mp[d]);
        }
        __syncthreads();
        if (half == 0) {
            #pragma unroll
            for (int d = 0; d < 8; ++d)
                acc += mp[d] * expf(-10.f * mp[d]) * exch[d * 256 + tl];
        }
        __syncthreads();                           // exch free for next slice
    }

    // block reduction (upper half contributes 0)
    #pragma unroll
    for (int off = 32; off; off >>= 1) acc += __shfl_down(acc, off);
    int lane = t & 63, wv = t >> 6;                // 8 waves
    if (lane == 0) exch[wv] = acc;
    __syncthreads();
    if (t == 0) {
        float v = 0.f;
        #pragma unroll
        for (int k = 0; k < 8; ++k) v += exch[k];
        atomicAdd(out, v * scale);
    }
}

// ---------------- host orchestration ----------------
// Round-7 champion pipeline; final stage = paired LDS-exchange fusion.
// G=g -> dual9(G->A,B) -> davg8(A,B,G->C=gn1) -> avg_abs(G->A=go)
// -> dual7(A->B=max7, G=min7) -> davg_final2(B,G,A,C -> atomicAdd out).

extern "C" void kernel_launch(void* const* d_in, const int* in_sizes, int n_in,
                              void* d_out, int out_size, void* d_ws, size_t ws_size,
                              hipStream_t stream) {
    const float* Rrgb = (const float*)d_in[0];
    const float* Lrgb = (const float*)d_in[1];
    float* out = (float*)d_out;
    float* w = (float*)d_ws;
    const float scale = 1.f / (float)P16N;
    const int gradblk = (P16N / 4 + 255) / 256;

    hipMemsetAsync(out, 0, sizeof(float) * (size_t)out_size, stream);

    const size_t stack64 = (size_t)64 * SS;
    if (ws_size >= 4 * stack64 * sizeof(float)) {
        // 4 buffers of 64 planes: layout [0..16)=Rgx [16..32)=Lgx [32..48)=Rgy [48..64)=Lgy
        float* G = w;
        float* A = G + stack64;
        float* B = A + stack64;
        float* C = B + stack64;
        grad_both<<<gradblk, 256, 0, stream>>>(Rrgb, G, 0, 32, 2);
        grad_both<<<gradblk, 256, 0, stream>>>(Lrgb, G, 16, 48, 2);
        int gp = 64 * (HH / 16);
        dual_pool<true, 4, 16><<<gp, 256, 0, stream>>>(G, A, B);          // A=max9|g|, B=min9|g|
        davg_pool<8, 1, 16><<<gp, 256, 0, stream>>>(A, B, G, nullptr, C); // C=gn1
        avg_abs_pool<2, 16><<<gp, 256, 0, stream>>>(G, A);                // A=go (G dead)
        dual_pool<false, 3, 16><<<gp, 256, 0, stream>>>(A, B, G);         // B=max7, G=min7
        int fp = 32 * (HH / 16);
        davg_final2<3, 16><<<fp, 512, 0, stream>>>(B, G, A, C, out, scale);
    } else {
        // fallback: 4 buffers of 32 planes (128 MiB), one direction at a time
        const size_t stack32 = (size_t)32 * SS;
        float* G = w;
        float* A = G + stack32;
        float* B = A + stack32;
        float* C = B + stack32;
        for (int dir = 0; dir < 2; ++dir) {
            grad_both<<<gradblk, 256, 0, stream>>>(Rrgb, G, 0, 0, dir);
            grad_both<<<gradblk, 256, 0, stream>>>(Lrgb, G, 16, 16, dir);
            int gp = 32 * (HH / 16);
            dual_pool<true, 4, 16><<<gp, 256, 0, stream>>>(G, A, B);
            davg_pool<8, 1, 16><<<gp, 256, 0, stream>>>(A, B, G, nullptr, C);
            avg_abs_pool<2, 16><<<gp, 256, 0, stream>>>(G, A);
            dual_pool<false, 3, 16><<<gp, 256, 0, stream>>>(A, B, G);
            int fp = 16 * (HH / 16);
            davg_final2<3, 16><<<fp, 512, 0, stream>>>(B, G, A, C, out, scale);
        }
    }
}

// Round 10
// 364.862 us; speedup vs baseline: 1.3215x; 1.0244x over previous
//
#include <hip/hip_runtime.h>

#define HH 512
#define WW 512
#define SS (HH * WW)          // elements per plane (2^18)
#define P16N (16 * SS)        // 16 planes (2^22)
#define PADW 576              // skewed LDS row: addr(j) = j + (j>>3)
#define HALFW 544             // dual-half row: 512 + 32 pad, skew j + (j>>4)
#define DPADW (2 * HALFW)     // [s1-colsums : 544 | s2-colsums : 544]

constexpr float FINF = 3.402823466e38f;

__device__ __forceinline__ int swz(int j)  { return j + (j >> 3); }
__device__ __forceinline__ int swz2(int j) { return j + (j >> 4); }   // <=2-way, free

__device__ __forceinline__ float gray1(float r, float g, float b) {
    return 0.299f * r + 0.587f * g + 0.114f * b;
}

// inverse of small integer c in [R+1, 2R+1] without v_div (cmp+cndmask chain)
template <int R>
__device__ __forceinline__ float invsmall(int c) {
    float r = 1.f / (float)(2 * R + 1);
    #pragma unroll
    for (int v = R + 1; v < 2 * R + 1; ++v)
        if (c == v) r = 1.f / (float)v;      // compile-time constants
    return r;
}

// ---------------- grad (gray fused, both dirs, 4 px/thread) ----------------
__global__ __launch_bounds__(256) void grad_both(const float* __restrict__ rgb,
                                                 float* __restrict__ dst,
                                                 int gxp0, int gyp0, int dirsel) {
    int sp = blockIdx.x * 256 + threadIdx.x;
    int idx = sp << 2;                             // [0, P16N)
    int img = idx >> 18;
    int pix = idx & (SS - 1);
    int i = pix >> 9, j0 = pix & (WW - 1);
    const float* p0 = rgb + (size_t)img * 3 * SS + pix;

    float4 r = *(const float4*)p0;
    float4 g = *(const float4*)(p0 + SS);
    float4 b = *(const float4*)(p0 + 2 * SS);
    float4 gy4 = make_float4(gray1(r.x, g.x, b.x), gray1(r.y, g.y, b.y),
                             gray1(r.z, g.z, b.z), gray1(r.w, g.w, b.w));
    if (dirsel != 1) {
        float grs = 0.f;
        if (j0 + 4 < WW) grs = gray1(p0[4], p0[SS + 4], p0[2 * SS + 4]);
        float4 gx = make_float4(gy4.x - gy4.y, gy4.y - gy4.z, gy4.z - gy4.w, gy4.w - grs);
        *(float4*)(dst + (size_t)(gxp0 + img) * SS + pix) = gx;
    }
    if (dirsel != 0) {
        float4 gd = make_float4(0.f, 0.f, 0.f, 0.f);
        if (i < HH - 1) {
            float4 r2 = *(const float4*)(p0 + WW);
            float4 g2 = *(const float4*)(p0 + SS + WW);
            float4 b2 = *(const float4*)(p0 + 2 * SS + WW);
            gd = make_float4(gray1(r2.x, g2.x, b2.x), gray1(r2.y, g2.y, b2.y),
                             gray1(r2.z, g2.z, b2.z), gray1(r2.w, g2.w, b2.w));
        }
        float4 gy = make_float4(gy4.x - gd.x, gy4.y - gd.y, gy4.z - gd.z, gy4.w - gd.w);
        *(float4*)(dst + (size_t)(gyp0 + img) * SS + pix) = gy;
    }
}

// ---------------- dual max+min pool (column-first, skewed LDS) ----------------
// SINGLE ring buffer rb[W]; exact wrap-counted validity mask (compile-time
// except i0). Phase-split over ONE LDS buffer (36864 B -> 4 blocks/CU):
// vertical max -> LDS, min -> regs; hmax -> dmax; reload; hmin -> dmin.
template <bool PREABS, int R, int TH>
__global__ __launch_bounds__(256, 4) void dual_pool(const float* __restrict__ src,
                                                    float* __restrict__ dmax,
                                                    float* __restrict__ dmin) {
    constexpr int TILES = HH / TH;
    constexpr int W = 2 * R + 1;
    constexpr int NS = (TH * 64) / 256;
    __shared__ float lbuf[TH * PADW];

    const int plane = blockIdx.x / TILES;
    const int tile  = blockIdx.x % TILES;
    const int i0    = tile * TH;
    const size_t pbase = (size_t)plane * SS;
    const float* sp = src + pbase;
    const int t = threadIdx.x;
    const int ca = swz(2 * t);                     // ca+1 == swz(2t+1)

    float2 rb[W];
    float2 keepmn[TH];
    auto ld = [&](int gi) -> float2 {
        float2 u = ((const float2*)(sp + (size_t)gi * WW))[t];
        if (PREABS) { u.x = fabsf(u.x); u.y = fabsf(u.y); }
        return u;
    };
    #pragma unroll
    for (int k = 0; k < W; ++k)
        if ((unsigned)(i0 - R + k) < (unsigned)HH) rb[k] = ld(i0 - R + k);
    #pragma unroll
    for (int oi = 0; oi < TH; ++oi) {
        if (oi > 0) {
            if ((unsigned)(i0 + oi + R) < (unsigned)HH) rb[(oi - 1) % W] = ld(i0 + oi + R);
        }
        float2 mx = make_float2(-FINF, -FINF), mn = make_float2(FINF, FINF);
        #pragma unroll
        for (int k = 0; k < W; ++k) {
            int wrap = (oi > k) ? ((oi - 1 - k) / W + 1) : 0;   // compile-time
            int ro = k - R + wrap * W;                          // exact row in slot k
            if ((unsigned)(i0 + ro) < (unsigned)HH) {           // block-uniform branch
                mx.x = fmaxf(mx.x, rb[k].x); mx.y = fmaxf(mx.y, rb[k].y);
                mn.x = fminf(mn.x, rb[k].x); mn.y = fminf(mn.y, rb[k].y);
            }
        }
        lbuf[oi * PADW + ca] = mx.x; lbuf[oi * PADW + ca + 1] = mx.y;
        keepmn[oi] = mn;
    }
    __syncthreads();

    // horizontal max -> dmax
    #pragma unroll
    for (int si = 0; si < NS; ++si) {
        int s = si * 256 + t;
        int rr = s >> 6, j0 = (s & 63) << 3;
        const float* rx = &lbuf[rr * PADW];
        float vx[2 * R + 8];
        #pragma unroll
        for (int k = 0; k < 2 * R + 8; ++k) {
            int jj = j0 - R + k;
            bool ok = (unsigned)jj < (unsigned)WW;
            int jc = swz(min(max(jj, 0), WW - 1));
            vx[k] = ok ? rx[jc] : -FINF;
        }
        float ox[8];
        #pragma unroll
        for (int d = 0; d < 8; ++d) {
            float mx = vx[d];
            #pragma unroll
            for (int k = 1; k <= 2 * R; ++k) mx = fmaxf(mx, vx[d + k]);
            ox[d] = mx;
        }
        size_t o = pbase + (size_t)(i0 + rr) * WW + j0;
        ((float4*)&dmax[o])[0] = make_float4(ox[0], ox[1], ox[2], ox[3]);
        ((float4*)&dmax[o])[1] = make_float4(ox[4], ox[5], ox[6], ox[7]);
    }
    __syncthreads();

    // swap in the vertical-min column results
    #pragma unroll
    for (int oi = 0; oi < TH; ++oi) {
        lbuf[oi * PADW + ca] = keepmn[oi].x;
        lbuf[oi * PADW + ca + 1] = keepmn[oi].y;
    }
    __syncthreads();

    // horizontal min -> dmin
    #pragma unroll
    for (int si = 0; si < NS; ++si) {
        int s = si * 256 + t;
        int rr = s >> 6, j0 = (s & 63) << 3;
        const float* rn = &lbuf[rr * PADW];
        float vn[2 * R + 8];
        #pragma unroll
        for (int k = 0; k < 2 * R + 8; ++k) {
            int jj = j0 - R + k;
            bool ok = (unsigned)jj < (unsigned)WW;
            int jc = swz(min(max(jj, 0), WW - 1));
            vn[k] = ok ? rn[jc] : FINF;
        }
        float on[8];
        #pragma unroll
        for (int d = 0; d < 8; ++d) {
            float mn = vn[d];
            #pragma unroll
            for (int k = 1; k <= 2 * R; ++k) mn = fminf(mn, vn[d + k]);
            on[d] = mn;
        }
        size_t o = pbase + (size_t)(i0 + rr) * WW + j0;
        ((float4*)&dmin[o])[0] = make_float4(on[0], on[1], on[2], on[3]);
        ((float4*)&dmin[o])[1] = make_float4(on[4], on[5], on[6], on[7]);
    }
}

// ---------------- single avg pool (abs output), division-free ----------------
template <int R, int TH>
__global__ __launch_bounds__(256, 4) void avg_abs_pool(const float* __restrict__ src,
                                                       float* __restrict__ dst) {
    constexpr int TILES = HH / TH;
    __shared__ float ls[TH * PADW];
    const int plane = blockIdx.x / TILES;
    const int tile  = blockIdx.x % TILES;
    const int i0    = tile * TH;
    const size_t pbase = (size_t)plane * SS;
    const float* sp = src + pbase;
    const int t = threadIdx.x;

    auto ld = [&](int gi) -> float2 {
        if ((unsigned)gi < (unsigned)HH) return ((const float2*)(sp + (size_t)gi * WW))[t];
        return make_float2(0.f, 0.f);
    };
    float2 acc = make_float2(0.f, 0.f);
    #pragma unroll
    for (int k = -R; k <= R; ++k) { float2 v = ld(i0 + k); acc.x += v.x; acc.y += v.y; }
    const int ca = swz(2 * t);
    ls[ca] = acc.x; ls[ca + 1] = acc.y;
    #pragma unroll
    for (int oi = 1; oi < TH; ++oi) {
        float2 a = ld(i0 + oi + R), s = ld(i0 + oi - R - 1);
        acc.x += a.x - s.x; acc.y += a.y - s.y;
        ls[oi * PADW + ca] = acc.x; ls[oi * PADW + ca + 1] = acc.y;
    }
    __syncthreads();

    for (int s = t; s < TH * 64; s += 256) {
        int rr = s >> 6, j0 = (s & 63) << 3;
        int i = i0 + rr;
        int ch = min(i + R, HH - 1) - max(i - R, 0) + 1;
        float invch = invsmall<R>(ch);
        const float* row = &ls[rr * PADW];
        int lo = max(j0 - R, 0), hi = min(j0 + R, WW - 1);
        float racc = 0.f;
        for (int jj = lo; jj <= hi; ++jj) racc += row[swz(jj)];
        float ov[8];
        #pragma unroll
        for (int d = 0; d < 8; ++d) {
            if (d > 0) {
                int add = j0 + d + R, sub = j0 + d - R - 1;
                if (add < WW) racc += row[swz(add)];
                if (sub >= 0) racc -= row[swz(sub)];
            }
            int j = j0 + d;
            int cw = min(j + R, WW - 1) - max(j - R, 0) + 1;
            ov[d] = fabsf(racc * (invch * invsmall<R>(cw)));
        }
        float4* d4 = (float4*)&dst[pbase + (size_t)i * WW + j0];
        d4[0] = make_float4(ov[0], ov[1], ov[2], ov[3]);
        d4[1] = make_float4(ov[4], ov[5], ov[6], ov[7]);
    }
}

// ---------------- fused gn1: dual-stream avg17 + epilogue, SINGLE pass ----------------
// out = (|e1|*chcw - racc2)/(|racc1 - racc2| + 1e-4*chcw)
// s1 and s2 rows read TOGETHER (two independent load streams -> 2x MLP in the
// latency-bound vertical phase). Dual-half LDS rows [s1:544|s2:544], swz2 skew.
// NO keep1 array (the spill hazard). 8-row streamed window: 34816 B -> 4 blk/CU.
template <int R, int TH, int SUB>
__global__ __launch_bounds__(256, 4) void gn1_fused(const float* __restrict__ s1,
                                                    const float* __restrict__ s2,
                                                    const float* __restrict__ e1,
                                                    float* __restrict__ dst) {
    constexpr int TILES = HH / TH;
    constexpr int NSP = TH / SUB;
    constexpr int NSH = (SUB * 64) / 256;
    __shared__ float lbuf[SUB * DPADW];
    const int plane = blockIdx.x / TILES;
    const int tile  = blockIdx.x % TILES;
    const int i0    = tile * TH;
    const size_t pbase = (size_t)plane * SS;
    const float* sp1 = s1 + pbase;
    const float* sp2 = s2 + pbase;
    const int t = threadIdx.x;
    const int ca = swz2(2 * t);                    // ca+1 == swz2(2t+1)

    auto ld = [&](const float* sp, int gi) -> float2 {
        if ((unsigned)gi < (unsigned)HH) return ((const float2*)(sp + (size_t)gi * WW))[t];
        return make_float2(0.f, 0.f);
    };
    float2 a1 = make_float2(0.f, 0.f), a2 = make_float2(0.f, 0.f);
    #pragma unroll
    for (int k = -R; k <= R; ++k) {
        float2 u = ld(sp1, i0 + k); a1.x += u.x; a1.y += u.y;
        float2 v = ld(sp2, i0 + k); a2.x += v.x; a2.y += v.y;
    }

    #pragma unroll
    for (int p = 0; p < NSP; ++p) {
        if (p > 0) __syncthreads();                // window free (prev horizontal done)
        #pragma unroll
        for (int q = 0; q < SUB; ++q) {
            const int oi = p * SUB + q;
            if (oi > 0) {
                float2 u = ld(sp1, i0 + oi + R), us = ld(sp1, i0 + oi - R - 1);
                a1.x += u.x - us.x; a1.y += u.y - us.y;
                float2 v = ld(sp2, i0 + oi + R), vs = ld(sp2, i0 + oi - R - 1);
                a2.x += v.x - vs.x; a2.y += v.y - vs.y;
            }
            lbuf[q * DPADW + ca] = a1.x;         lbuf[q * DPADW + ca + 1] = a1.y;
            lbuf[q * DPADW + HALFW + ca] = a2.x; lbuf[q * DPADW + HALFW + ca + 1] = a2.y;
        }
        __syncthreads();

        #pragma unroll
        for (int si = 0; si < NSH; ++si) {
            int s = si * 256 + t;
            int rr = s >> 6, j0 = (s & 63) << 3;
            int i = i0 + p * SUB + rr;
            int ch = min(i + R, HH - 1) - max(i - R, 0) + 1;
            const float* rowA = &lbuf[rr * DPADW];
            const float* rowB = rowA + HALFW;
            size_t rowbase = pbase + (size_t)i * WW + j0;

            float e1v[8];
            {
                float4 q0 = ((const float4*)(e1 + rowbase))[0];
                float4 q1 = ((const float4*)(e1 + rowbase))[1];
                e1v[0]=q0.x; e1v[1]=q0.y; e1v[2]=q0.z; e1v[3]=q0.w;
                e1v[4]=q1.x; e1v[5]=q1.y; e1v[6]=q1.z; e1v[7]=q1.w;
            }

            int lo = max(j0 - R, 0), hi = min(j0 + R, WW - 1);
            float r1 = 0.f, r2 = 0.f;
            for (int jj = lo; jj <= hi; ++jj) {
                int jc = swz2(jj);
                r1 += rowA[jc]; r2 += rowB[jc];
            }
            float ov[8];
            #pragma unroll
            for (int d = 0; d < 8; ++d) {
                if (d > 0) {
                    int add = j0 + d + R, sub = j0 + d - R - 1;
                    if (add < WW) { int jc = swz2(add); r1 += rowA[jc]; r2 += rowB[jc]; }
                    if (sub >= 0) { int jc = swz2(sub); r1 -= rowA[jc]; r2 -= rowB[jc]; }
                }
                int j = j0 + d;
                int cw = min(j + R, WW - 1) - max(j - R, 0) + 1;
                float chcw = (float)(ch * cw);
                float den = fabsf(r1 - r2) + 1e-4f * chcw;
                ov[d] = (fabsf(e1v[d]) * chcw - r2) / den;
            }
            float4* d4 = (float4*)&dst[rowbase];
            d4[0] = make_float4(ov[0], ov[1], ov[2], ov[3]);
            d4[1] = make_float4(ov[4], ov[5], ov[6], ov[7]);
        }
    }
}

// ---------------- fused final: dual-stream avg7 + map + paired reduction ----------------
// 512 threads: lower half = plane R, upper half = plane L (=R+16). Single vert
// pass over s1,s2 together (no keep1); dual-half LDS rows; 8-row window.
// Per slice: L-half posts exp(-10*mapL) via exch, R-half accumulates
// mapR*exp(-10*mapR)*exch. LDS = 2*8*1088*4 + 8192 = 77824 B -> 2 blk/CU.
template <int R, int TH, int SUB>
__global__ __launch_bounds__(512, 4) void final_fused(const float* __restrict__ s1,
                                                      const float* __restrict__ s2,
                                                      const float* __restrict__ e1,
                                                      const float* __restrict__ e2,
                                                      float* __restrict__ out, float scale) {
    constexpr int TILES = HH / TH;
    constexpr int NSP = TH / SUB;
    constexpr int NSH = (SUB * 64) / 256;
    __shared__ float lbuf[2 * SUB * DPADW];        // 69632 B
    __shared__ float exch[2048];                   // 8192 B (also final reduction)

    const int t    = threadIdx.x;
    const int half = t >> 8;                       // 0 = R-plane, 1 = L-plane
    const int tl   = t & 255;
    const int pairidx = blockIdx.x / TILES;
    const int tile    = blockIdx.x % TILES;
    const int i0      = tile * TH;
    const int planeR  = pairidx + ((pairidx >> 4) << 4);   // 0..15->0..15; 16..31->32..47
    const size_t pbase = (size_t)(planeR + half * 16) * SS;
    const float* sp1 = s1 + pbase;
    const float* sp2 = s2 + pbase;
    float* myl = lbuf + half * (SUB * DPADW);
    const int ca = swz2(2 * tl);

    auto ld = [&](const float* sp, int gi) -> float2 {
        if ((unsigned)gi < (unsigned)HH) return ((const float2*)(sp + (size_t)gi * WW))[tl];
        return make_float2(0.f, 0.f);
    };
    float2 a1 = make_float2(0.f, 0.f), a2 = make_float2(0.f, 0.f);
    #pragma unroll
    for (int k = -R; k <= R; ++k) {
        float2 u = ld(sp1, i0 + k); a1.x += u.x; a1.y += u.y;
        float2 v = ld(sp2, i0 + k); a2.x += v.x; a2.y += v.y;
    }

    float acc = 0.f;
    #pragma unroll
    for (int p = 0; p < NSP; ++p) {
        if (p > 0) __syncthreads();
        #pragma unroll
        for (int q = 0; q < SUB; ++q) {
            const int oi = p * SUB + q;
            if (oi > 0) {
                float2 u = ld(sp1, i0 + oi + R), us = ld(sp1, i0 + oi - R - 1);
                a1.x += u.x - us.x; a1.y += u.y - us.y;
                float2 v = ld(sp2, i0 + oi + R), vs = ld(sp2, i0 + oi - R - 1);
                a2.x += v.x - vs.x; a2.y += v.y - vs.y;
            }
            myl[q * DPADW + ca] = a1.x;         myl[q * DPADW + ca + 1] = a1.y;
            myl[q * DPADW + HALFW + ca] = a2.x; myl[q * DPADW + HALFW + ca + 1] = a2.y;
        }
        __syncthreads();

        #pragma unroll
        for (int si = 0; si < NSH; ++si) {
            int s = si * 256 + tl;
            int rr = s >> 6, j0 = (s & 63) << 3;
            int i = i0 + p * SUB + rr;
            int ch = min(i + R, HH - 1) - max(i - R, 0) + 1;
            const float* rowA = &myl[rr * DPADW];
            const float* rowB = rowA + HALFW;
            size_t rowbase = pbase + (size_t)i * WW + j0;

            float e1v[8], e2v[8];
            {
                float4 q0 = ((const float4*)(e1 + rowbase))[0];
                float4 q1 = ((const float4*)(e1 + rowbase))[1];
                e1v[0]=q0.x; e1v[1]=q0.y; e1v[2]=q0.z; e1v[3]=q0.w;
                e1v[4]=q1.x; e1v[5]=q1.y; e1v[6]=q1.z; e1v[7]=q1.w;
                float4 b0 = ((const float4*)(e2 + rowbase))[0];
                float4 b1 = ((const float4*)(e2 + rowbase))[1];
                e2v[0]=b0.x; e2v[1]=b0.y; e2v[2]=b0.z; e2v[3]=b0.w;
                e2v[4]=b1.x; e2v[5]=b1.y; e2v[6]=b1.z; e2v[7]=b1.w;
            }

            int lo = max(j0 - R, 0), hi = min(j0 + R, WW - 1);
            float r1 = 0.f, r2 = 0.f;
            for (int jj = lo; jj <= hi; ++jj) {
                int jc = swz2(jj);
                r1 += rowA[jc]; r2 += rowB[jc];
            }
            float mp[8];
            #pragma unroll
            for (int d = 0; d < 8; ++d) {
                if (d > 0) {
                    int add = j0 + d + R, sub = j0 + d - R - 1;
                    if (add < WW) { int jc = swz2(add); r1 += rowA[jc]; r2 += rowB[jc]; }
                    if (sub >= 0) { int jc = swz2(sub); r1 -= rowA[jc]; r2 -= rowB[jc]; }
                }
                int j = j0 + d;
                int cw = min(j + R, WW - 1) - max(j - R, 0) + 1;
                float chcw = (float)(ch * cw);
                float den = fabsf(r1 - r2) + 1e-4f * chcw;
                mp[d] = ((e1v[d] * chcw - r2) / den + 0.01f) * e2v[d];
            }
            if (half == 1) {                       // wave-uniform
                #pragma unroll
                for (int d = 0; d < 8; ++d) exch[d * 256 + tl] = expf(-10.f * mp[d]);
            }
            __syncthreads();
            if (half == 0) {
                #pragma unroll
                for (int d = 0; d < 8; ++d)
                    acc += mp[d] * expf(-10.f * mp[d]) * exch[d * 256 + tl];
            }
            __syncthreads();                       // exch free for next slice
        }
    }

    // block reduction (upper half contributes 0)
    #pragma unroll
    for (int off = 32; off; off >>= 1) acc += __shfl_down(acc, off);
    int lane = t & 63, wv = t >> 6;                // 8 waves
    if (lane == 0) exch[wv] = acc;
    __syncthreads();
    if (t == 0) {
        float v = 0.f;
        #pragma unroll
        for (int k = 0; k < 8; ++k) v += exch[k];
        atomicAdd(out, v * scale);
    }
}

// ---------------- host orchestration ----------------
// Champion pipeline; both davg-class kernels merged to single-pass dual-stream.
// G=g -> dual9(G->A,B) -> gn1_fused(A,B,G->C=gn1) -> avg_abs(G->A=go)
// -> dual7(A->B=max7, G=min7) -> final_fused(B,G,A,C -> atomicAdd out).

extern "C" void kernel_launch(void* const* d_in, const int* in_sizes, int n_in,
                              void* d_out, int out_size, void* d_ws, size_t ws_size,
                              hipStream_t stream) {
    const float* Rrgb = (const float*)d_in[0];
    const float* Lrgb = (const float*)d_in[1];
    float* out = (float*)d_out;
    float* w = (float*)d_ws;
    const float scale = 1.f / (float)P16N;
    const int gradblk = (P16N / 4 + 255) / 256;

    hipMemsetAsync(out, 0, sizeof(float) * (size_t)out_size, stream);

    const size_t stack64 = (size_t)64 * SS;
    if (ws_size >= 4 * stack64 * sizeof(float)) {
        // 4 buffers of 64 planes: layout [0..16)=Rgx [16..32)=Lgx [32..48)=Rgy [48..64)=Lgy
        float* G = w;
        float* A = G + stack64;
        float* B = A + stack64;
        float* C = B + stack64;
        grad_both<<<gradblk, 256, 0, stream>>>(Rrgb, G, 0, 32, 2);
        grad_both<<<gradblk, 256, 0, stream>>>(Lrgb, G, 16, 48, 2);
        int gp = 64 * (HH / 16);
        dual_pool<true, 4, 16><<<gp, 256, 0, stream>>>(G, A, B);          // A=max9|g|, B=min9|g|
        gn1_fused<8, 16, 8><<<gp, 256, 0, stream>>>(A, B, G, C);          // C=gn1
        avg_abs_pool<2, 16><<<gp, 256, 0, stream>>>(G, A);                // A=go (G dead)
        dual_pool<false, 3, 16><<<gp, 256, 0, stream>>>(A, B, G);         // B=max7, G=min7
        int fp = 32 * (HH / 16);
        final_fused<3, 16, 8><<<fp, 512, 0, stream>>>(B, G, A, C, out, scale);
    } else {
        // fallback: 4 buffers of 32 planes (128 MiB), one direction at a time
        const size_t stack32 = (size_t)32 * SS;
        float* G = w;
        float* A = G + stack32;
        float* B = A + stack32;
        float* C = B + stack32;
        for (int dir = 0; dir < 2; ++dir) {
            grad_both<<<gradblk, 256, 0, stream>>>(Rrgb, G, 0, 0, dir);
            grad_both<<<gradblk, 256, 0, stream>>>(Lrgb, G, 16, 16, dir);
            int gp = 32 * (HH / 16);
            dual_pool<true, 4, 16><<<gp, 256, 0, stream>>>(G, A, B);
            gn1_fused<8, 16, 8><<<gp, 256, 0, stream>>>(A, B, G, C);
            avg_abs_pool<2, 16><<<gp, 256, 0, stream>>>(G, A);
            dual_pool<false, 3, 16><<<gp, 256, 0, stream>>>(A, B, G);
            int fp = 16 * (HH / 16);
            final_fused<3, 16, 8><<<fp, 512, 0, stream>>>(B, G, A, C, out, scale);
        }
    }
}